// Round 11
// baseline (98.595 us; speedup 1.0000x reference)
//
#include <hip/hip_runtime.h>
#include <math.h>

typedef _Float16 f16;
typedef _Float16 f16x4 __attribute__((ext_vector_type(4)));
typedef _Float16 f16x8 __attribute__((ext_vector_type(8)));
typedef float f32x4 __attribute__((ext_vector_type(4)));

#define S_TOTAL 16384
#define N_NODES 512
#define N_PIPES 1024
#define N_DEM   256
#define HIDDEN  64
#define T_SCALE 256.0f   // t = (supply - hL)/T_SCALE to fit f16 range; H *= T_SCALE

// direct HBM -> LDS, 16B per lane (wave writes base + lane*16, LINEAR dest)
#define GLOAD16(gsrc, ldst) \
    __builtin_amdgcn_global_load_lds((const __attribute__((address_space(1))) void*)(gsrc), \
                                     (__attribute__((address_space(3))) void*)(ldst), 16, 0, 0)
#define SBAR()  __builtin_amdgcn_s_barrier()
#define FENCE() asm volatile("" ::: "memory")
#define WAITN(n) asm volatile("s_waitcnt vmcnt(" #n ")" ::: "memory")
#define LGKM0() asm volatile("s_waitcnt lgkmcnt(0)" ::: "memory")

// ================= fused prep: MLP + transposes + conversions + gathers ========
// blocks [0,256):   MLP (4 waves/block, 1 pipe/wave) + d_out zero (block 0)
// blocks [256,512): transpose M (128) and inv (128) to f16 [C][R]
// blocks [512,1024): grid-stride conversions + gathers (no D conversion anymore)
__global__ __launch_bounds__(256) void prep_all(
    const float* __restrict__ W1, const float* __restrict__ b1,
    const float* __restrict__ W2, const float* __restrict__ b2,
    const float* __restrict__ W3, const float* __restrict__ b3,
    const float* __restrict__ base,
    const float* __restrict__ L, const float* __restrict__ dpipe,
    const float* __restrict__ Cw,
    const float* __restrict__ Mf, const float* __restrict__ inv,
    const float* __restrict__ A0,
    const int* __restrict__ dmap,
    float* __restrict__ net, float* __restrict__ lKc,
    f16* __restrict__ MT16, f16* __restrict__ invT16,
    f16* __restrict__ inv16, f16* __restrict__ A016,
    f16* __restrict__ DI16, f16* __restrict__ IDXT,
    float* __restrict__ out, int out_size)
{
    __shared__ __align__(16) f16 tile[64][72];
    const int b = blockIdx.x, t = threadIdx.x;
    if (b < 256) {
        if (b == 0) for (int i = t; i < out_size; i += 256) out[i] = 0.f;
        const int wid = t >> 6, k = t & 63;
        const int p = b * 4 + wid;
        const float x = (float)p;
        float h1 = tanhf(x * W1[k] + b1[k]);
        float acc = b2[k];
        #pragma unroll
        for (int j = 0; j < HIDDEN; ++j) {
            float hj = __shfl(h1, j, 64);
            acc = fmaf(hj, W2[j * HIDDEN + k], acc);
        }
        float partial = tanhf(acc) * W3[k];
        #pragma unroll
        for (int off = 32; off > 0; off >>= 1) partial += __shfl_down(partial, off, 64);
        if (k == 0) {
            net[p] = base[p] + partial + b3[0];
            lKc[p] = log2f(10.667f) - 1.852f * log2f(Cw[p]) - 4.871f * log2f(dpipe[p]) + log2f(L[p]);
        }
        return;
    }
    if (b < 512) {
        const int idx = b - 256;
        const float* in = (idx < 128) ? Mf : inv;
        f16* outp = (idx < 128) ? MT16 : invT16;
        const int i2 = idx & 127;
        const int bx = i2 & 15, by = i2 >> 4;   // 16 x 8 tiles of 64x64
        const int r0 = by * 64, c0 = bx * 64;
        const int lr = t / 16, lc4 = (t % 16) * 4;
        #pragma unroll
        for (int i = 0; i < 4; ++i) {
            int r = lr + i * 16;
            float4 v = *(const float4*)(in + (size_t)(r0 + r) * N_PIPES + c0 + lc4);
            tile[lc4 + 0][r] = (f16)v.x; tile[lc4 + 1][r] = (f16)v.y;
            tile[lc4 + 2][r] = (f16)v.z; tile[lc4 + 3][r] = (f16)v.w;
        }
        __syncthreads();
        const int wrow = t / 4, wc16 = (t % 4) * 16;
        *(f16x8*)(outp + (size_t)(c0 + wrow) * N_NODES + r0 + wc16)     = *(f16x8*)&tile[wrow][wc16];
        *(f16x8*)(outp + (size_t)(c0 + wrow) * N_NODES + r0 + wc16 + 8) = *(f16x8*)&tile[wrow][wc16 + 8];
        return;
    }
    const int tid = (b - 512) * 256 + t;
    const int np = 512 * 256;
    for (int i = tid; i < (N_NODES * N_PIPES) / 4; i += np) {
        float4 v = ((const float4*)inv)[i];
        ((f16x4*)inv16)[i] = (f16x4){(f16)v.x, (f16)v.y, (f16)v.z, (f16)v.w};
        float4 w = ((const float4*)A0)[i];
        ((f16x4*)A016)[i] = (f16x4){(f16)w.x, (f16)w.y, (f16)w.z, (f16)w.w};
    }
    for (int i = tid; i < N_DEM * (N_PIPES / 4); i += np) {
        int j = i >> 8, p0 = (i & 255) * 4;
        float4 v = *(const float4*)(inv + (size_t)dmap[j] * N_PIPES + p0);
        *(f16x4*)(DI16 + (size_t)j * N_PIPES + p0) = (f16x4){(f16)v.x, (f16)v.y, (f16)v.z, (f16)v.w};
    }
    for (int i = tid; i < N_PIPES * (N_DEM / 4); i += np) {
        int p = i >> 6, j0 = (i & 63) * 4;
        f16x4 o;
        #pragma unroll
        for (int u = 0; u < 4; ++u)
            o[u] = (f16)inv[(size_t)dmap[j0 + u] * N_PIPES + p];
        *(f16x4*)(IDXT + (size_t)p * N_DEM + j0) = o;
    }
}

// ---------------- small MFMA GEMM body (256 thr): C[i][c] = sum_k A[i][k]*B[c][k]
struct GemmP {
    const f16* A; int lda;
    const f16* B; int ldb;
    f16* C; int ldc;
    int K;
    const int* dmap;
    int gx, gy;
};

__device__ __forceinline__ void gemm_body(const GemmP& P, int bx, int by) {
    __shared__ __align__(16) f16 As[128][72], Bs[64][72];
    const int m0 = by * 128, c0 = bx * 64;
    const int t = threadIdx.x, lane = t & 63, wid = t >> 6;
    const int wr = wid >> 1, wc = wid & 1;
    const int cl = lane & 15, g = lane >> 4;
    const int tr = t >> 3, tc = (t & 7) * 8;
    f32x4 acc[4][2] = {};
    for (int k0 = 0; k0 < P.K; k0 += 64) {
        #pragma unroll
        for (int r = 0; r < 4; ++r) {
            int row = r * 32 + tr;
            *(f16x8*)&As[row][tc] = *(const f16x8*)(P.A + (size_t)(m0 + row) * P.lda + k0 + tc);
        }
        #pragma unroll
        for (int r = 0; r < 2; ++r) {
            int row = r * 32 + tr;
            *(f16x8*)&Bs[row][tc] = *(const f16x8*)(P.B + (size_t)(c0 + row) * P.ldb + k0 + tc);
        }
        __syncthreads();
        #pragma unroll
        for (int kk = 0; kk < 2; ++kk) {
            const int kb = kk * 32 + g * 8;
            f16x8 a[4], bfr[2];
            #pragma unroll
            for (int m = 0; m < 4; ++m) a[m] = *(const f16x8*)&As[wr * 64 + m * 16 + cl][kb];
            #pragma unroll
            for (int n = 0; n < 2; ++n) bfr[n] = *(const f16x8*)&Bs[wc * 32 + n * 16 + cl][kb];
            #pragma unroll
            for (int m = 0; m < 4; ++m)
                #pragma unroll
                for (int n = 0; n < 2; ++n)
                    acc[m][n] = __builtin_amdgcn_mfma_f32_16x16x32_f16(a[m], bfr[n], acc[m][n], 0, 0, 0);
        }
        __syncthreads();
    }
    #pragma unroll
    for (int m = 0; m < 4; ++m)
        #pragma unroll
        for (int reg = 0; reg < 4; ++reg) {
            const int row = m0 + wr * 64 + m * 16 + g * 4 + reg;
            #pragma unroll
            for (int n = 0; n < 2; ++n) {
                const int col = c0 + wc * 32 + n * 16 + cl;
                float v = acc[m][n][reg];
                if (P.dmap && P.dmap[col] == row) v -= 1.0f;
                P.C[(size_t)row * P.ldc + col] = (f16)v;
            }
        }
}

__global__ __launch_bounds__(256) void gemm_small3(GemmP p0, GemmP p1, GemmP p2) {
    const GemmP& P = (blockIdx.z == 0) ? p0 : (blockIdx.z == 1) ? p1 : p2;
    if ((int)blockIdx.x >= P.gx || (int)blockIdx.y >= P.gy) return;
    gemm_body(P, blockIdx.x, blockIdx.y);
}

// ======================= gemm_qt + G2 rider (512 thr) ==========================
// y<128: q[s][p] = D*IDXT^T + nv*G16[idx]; t = (supply - hL)/T_SCALE
//   A-operand from f32 D, reg-staged + cvt, swizzled ds_write. B via gload_lds dbuf.
// y>=128: G2[i][c] = sum_k MT16[i][k]*Wt[c][k]  (1024x512, K=512)
__global__ __launch_bounds__(512, 4) void gemm_qt_mfma(
    const float* __restrict__ Df, const int* __restrict__ leak_id,
    const f16* __restrict__ IDXT, const float* __restrict__ net,
    const f16* __restrict__ G16, const float* __restrict__ lKc,
    const float* __restrict__ supply, f16* __restrict__ t16,
    const f16* __restrict__ MT16, const f16* __restrict__ Wt,
    f16* __restrict__ G2out)
{
    __shared__ __align__(16) f16 AsM[128 * 64];       // 16 KB single-buf A
    __shared__ __align__(16) f16 BsM[2][128 * 64];    // 32 KB dbuf B
    const int t = threadIdx.x, lane = t & 63, wid = t >> 6;

    if (blockIdx.y >= 128) {     // ---------------- G2 rider ----------------
        f16 (*A2)[72] = (f16(*)[72])&BsM[0][0];
        f16 (*B2)[72] = (f16(*)[72])&AsM[0];
        const int m0 = ((int)blockIdx.y - 128) * 128, c0 = blockIdx.x * 64;
        const int wr = wid >> 2, wc = wid & 3;
        const int cl = lane & 15, g = lane >> 4;
        f32x4 acc[4] = {};
        for (int k0 = 0; k0 < 512; k0 += 64) {
            {
                int r = t >> 2, c16 = (t & 3) * 16;
                *(f16x8*)&A2[r][c16]     = *(const f16x8*)(MT16 + (size_t)(m0 + r) * N_NODES + k0 + c16);
                *(f16x8*)&A2[r][c16 + 8] = *(const f16x8*)(MT16 + (size_t)(m0 + r) * N_NODES + k0 + c16 + 8);
                int r2 = t >> 3, c8 = (t & 7) * 8;
                *(f16x8*)&B2[r2][c8] = *(const f16x8*)(Wt + (size_t)(c0 + r2) * N_NODES + k0 + c8);
            }
            __syncthreads();
            #pragma unroll
            for (int kk = 0; kk < 2; ++kk) {
                const int kb = kk * 32 + g * 8;
                f16x8 b = *(const f16x8*)&B2[wc * 16 + cl][kb];
                #pragma unroll
                for (int m = 0; m < 4; ++m) {
                    f16x8 a = *(const f16x8*)&A2[wr * 64 + m * 16 + cl][kb];
                    acc[m] = __builtin_amdgcn_mfma_f32_16x16x32_f16(a, b, acc[m], 0, 0, 0);
                }
            }
            __syncthreads();
        }
        #pragma unroll
        for (int m = 0; m < 4; ++m)
            #pragma unroll
            for (int reg = 0; reg < 4; ++reg)
                G2out[(size_t)(m0 + wr * 64 + m * 16 + g * 4 + reg) * N_NODES + c0 + wc * 16 + cl] = (f16)acc[m][reg];
        return;
    }
    // ---------------- qt tiles ----------------
    const int bid = blockIdx.y * 8 + blockIdx.x;           // 1024 blocks
    const int w = (bid & 7) * 128 + (bid >> 3);            // XCD-contiguous
    const int bx = w & 7, by = w >> 3;
    const int p0 = bx * 128, sb = by * 128;
    const int wr = wid >> 2, wc = wid & 3;                 // 2 x 4 waves
    const int cl = lane & 15, g = lane >> 4;
    const int swrow = lane >> 3;
    const int swp = ((lane & 7) ^ swrow) * 8;
    const int sx0 = (g ^ (cl & 7)) * 8, sx1 = ((4 + g) ^ (cl & 7)) * 8;

    f16 (*As)[64] = (f16(*)[64])AsM;
    const f16* Bbase = IDXT + (size_t)(p0 + swrow) * N_DEM + swp;

    const int arow = t >> 2, ah = t & 3;
    const int s0 = 2 * ah, s1 = 2 * ah + 1;
    const int gc0 = (s0 ^ (arow & 7)) * 8, gc1 = (s1 ^ (arow & 7)) * 8;
    const float* Drow = Df + (size_t)(sb + arow) * N_DEM;

    float4 a01, a02, a11, a12;
    auto A_load = [&](int k0) {
        a01 = *(const float4*)(Drow + k0 + gc0);
        a02 = *(const float4*)(Drow + k0 + gc0 + 4);
        a11 = *(const float4*)(Drow + k0 + gc1);
        a12 = *(const float4*)(Drow + k0 + gc1 + 4);
    };
    auto A_write = [&]() {
        f16x8 v0 = {(f16)a01.x, (f16)a01.y, (f16)a01.z, (f16)a01.w,
                    (f16)a02.x, (f16)a02.y, (f16)a02.z, (f16)a02.w};
        f16x8 v1 = {(f16)a11.x, (f16)a11.y, (f16)a11.z, (f16)a11.w,
                    (f16)a12.x, (f16)a12.y, (f16)a12.z, (f16)a12.w};
        *(f16x8*)&As[arow][s0 * 8] = v0;
        *(f16x8*)&As[arow][s1 * 8] = v1;
    };
    auto B_stage = [&](int buf, int k0) {
        #pragma unroll
        for (int c = 0; c < 2; ++c) {
            int r0 = c * 64 + wid * 8;
            GLOAD16(Bbase + (size_t)r0 * N_DEM + k0, &BsM[buf][r0 * 64]);
        }
    };
    f32x4 acc[4][2] = {};
    auto compute = [&](int buf) {
        #pragma unroll
        for (int kk = 0; kk < 2; ++kk) {
            const int sx = kk ? sx1 : sx0;
            f16x8 a[4], b[2];
            #pragma unroll
            for (int m = 0; m < 4; ++m) a[m] = *(const f16x8*)&As[wr * 64 + m * 16 + cl][sx];
            #pragma unroll
            for (int n = 0; n < 2; ++n) b[n] = *(const f16x8*)&BsM[buf][(wc * 32 + n * 16 + cl) * 64 + sx];
            #pragma unroll
            for (int m = 0; m < 4; ++m)
                #pragma unroll
                for (int n = 0; n < 2; ++n)
                    acc[m][n] = __builtin_amdgcn_mfma_f32_16x16x32_f16(a[m], b[n], acc[m][n], 0, 0, 0);
        }
    };

    A_load(0); B_stage(0, 0);
    int cur = 0;
    #pragma unroll 1
    for (int k = 0; k < 4; ++k) {
        WAITN(2);                 // A regs of tile k landed (B(k) 2 still out)
        SBAR();                   // all waves done reading As from tile k-1
        A_write(); LGKM0();
        if (k < 3) { A_load((k + 1) * 64); B_stage(cur ^ 1, (k + 1) * 64); WAITN(6); }
        else       { WAITN(0); }
        SBAR();                   // As written + B(k) landed, all waves
        compute(cur);
        cur ^= 1;
    }

    float lKc2[2], sup2[2]; int pcol[2];
    #pragma unroll
    for (int n = 0; n < 2; ++n) {
        pcol[n] = p0 + wc * 32 + n * 16 + cl;
        lKc2[n] = lKc[pcol[n]]; sup2[n] = supply[pcol[n]];
    }
    #pragma unroll
    for (int m = 0; m < 4; ++m) {
        #pragma unroll
        for (int reg = 0; reg < 4; ++reg) {
            const int srow = sb + wr * 64 + m * 16 + g * 4 + reg;
            const int idx = leak_id[srow];
            const float nv = net[idx];
            #pragma unroll
            for (int n = 0; n < 2; ++n) {
                float qv = acc[m][n][reg] + nv * (float)G16[(size_t)idx * N_PIPES + pcol[n]];
                float l = __builtin_amdgcn_logf(fabsf(qv));
                float hL = copysignf(__builtin_amdgcn_exp2f(fmaf(1.852f, l, lKc2[n])), qv);
                t16[(size_t)srow * N_PIPES + pcol[n]] = (f16)((sup2[n] - hL) * (1.0f / T_SCALE));
            }
        }
    }
}

// ======================= gemm_res (128x128, 8 waves, dbuf, swizzle) ============
// accH = t*inv^T (K=1024, gload dbuf); accR = D(f32)*P1'^T (K=256, reg-staged A)
__global__ __launch_bounds__(512, 4) void gemm_res_mfma(
    const f16* __restrict__ t16, const f16* __restrict__ inv16,
    const float* __restrict__ Df, const f16* __restrict__ P1p,
    const f16* __restrict__ MT16, const f16* __restrict__ G2_16,
    const int* __restrict__ leak_id, const float* __restrict__ net,
    const float* __restrict__ Cd_p, const float* __restrict__ a_p,
    float scale, float* __restrict__ out)
{
    __shared__ __align__(16) f16 AsM[2][128 * 64];
    __shared__ __align__(16) f16 BsM[2][128 * 64];
    const int nwg = gridDim.x * gridDim.y;
    const int bid = blockIdx.y * gridDim.x + blockIdx.x;
    const int w = (bid & 7) * (nwg >> 3) + (bid >> 3);
    const int bx = w % gridDim.x, by = w / gridDim.x;
    const int n0 = bx * 128, sb = by * 128;
    const int t = threadIdx.x, lane = t & 63, wid = t >> 6;
    const int wr = wid >> 2, wc = wid & 3;
    const int cl = lane & 15, g = lane >> 4;
    const int swrow = lane >> 3;
    const int swp = ((lane & 7) ^ swrow) * 8;
    const int sx0 = (g ^ (cl & 7)) * 8, sx1 = ((4 + g) ^ (cl & 7)) * 8;

    const f16* HAb = t16   + (size_t)(sb + swrow) * N_PIPES + swp;
    const f16* HBb = inv16 + (size_t)(n0 + swrow) * N_PIPES + swp;
    const f16* RBb = P1p   + (size_t)(n0 + swrow) * N_DEM + swp;

    f32x4 accH[4][2] = {}, accR[4][2] = {};

    auto stageH = [&](int buf, int k0) {
        #pragma unroll
        for (int c = 0; c < 2; ++c) {
            int r0 = c * 64 + wid * 8;
            GLOAD16(HAb + (size_t)r0 * N_PIPES + k0, &AsM[buf][r0 * 64]);
        }
        #pragma unroll
        for (int c = 0; c < 2; ++c) {
            int r0 = c * 64 + wid * 8;
            GLOAD16(HBb + (size_t)r0 * N_PIPES + k0, &BsM[buf][r0 * 64]);
        }
    };
    auto computeH = [&](int buf) {
        #pragma unroll
        for (int kk = 0; kk < 2; ++kk) {
            const int sx = kk ? sx1 : sx0;
            f16x8 a[4], b[2];
            #pragma unroll
            for (int m = 0; m < 4; ++m) a[m] = *(const f16x8*)&AsM[buf][(wr * 64 + m * 16 + cl) * 64 + sx];
            #pragma unroll
            for (int n = 0; n < 2; ++n) b[n] = *(const f16x8*)&BsM[buf][(wc * 32 + n * 16 + cl) * 64 + sx];
            #pragma unroll
            for (int m = 0; m < 4; ++m)
                #pragma unroll
                for (int n = 0; n < 2; ++n)
                    accH[m][n] = __builtin_amdgcn_mfma_f32_16x16x32_f16(a[m], b[n], accH[m][n], 0, 0, 0);
        }
    };

    int cur = 0;
    stageH(0, 0);
    #pragma unroll 1
    for (int k = 0; k < 15; ++k) {
        stageH(cur ^ 1, (k + 1) * 64);
        WAITN(4); SBAR();
        computeH(cur);
        FENCE(); SBAR();
        cur ^= 1;
    }
    WAITN(0); SBAR();
    computeH(cur);
    FENCE(); SBAR();                    // all H LDS reads complete

    // ---- R phase: A from f32 D reg-staged into AsM[0]; B = P1p gload dbuf ----
    const int arow = t >> 2, ah = t & 3;
    const int s0 = 2 * ah, s1 = 2 * ah + 1;
    const int gc0 = (s0 ^ (arow & 7)) * 8, gc1 = (s1 ^ (arow & 7)) * 8;
    const float* Drow = Df + (size_t)(sb + arow) * N_DEM;
    f16 (*Asr)[64] = (f16(*)[64])&AsM[0][0];

    float4 a01, a02, a11, a12;
    auto A_load = [&](int k0) {
        a01 = *(const float4*)(Drow + k0 + gc0);
        a02 = *(const float4*)(Drow + k0 + gc0 + 4);
        a11 = *(const float4*)(Drow + k0 + gc1);
        a12 = *(const float4*)(Drow + k0 + gc1 + 4);
    };
    auto A_write = [&]() {
        f16x8 v0 = {(f16)a01.x, (f16)a01.y, (f16)a01.z, (f16)a01.w,
                    (f16)a02.x, (f16)a02.y, (f16)a02.z, (f16)a02.w};
        f16x8 v1 = {(f16)a11.x, (f16)a11.y, (f16)a11.z, (f16)a11.w,
                    (f16)a12.x, (f16)a12.y, (f16)a12.z, (f16)a12.w};
        *(f16x8*)&Asr[arow][s0 * 8] = v0;
        *(f16x8*)&Asr[arow][s1 * 8] = v1;
    };
    auto B_stageR = [&](int buf, int k0) {
        #pragma unroll
        for (int c = 0; c < 2; ++c) {
            int r0 = c * 64 + wid * 8;
            GLOAD16(RBb + (size_t)r0 * N_DEM + k0, &BsM[buf][r0 * 64]);
        }
    };
    auto computeR = [&](int buf) {
        #pragma unroll
        for (int kk = 0; kk < 2; ++kk) {
            const int sx = kk ? sx1 : sx0;
            f16x8 a[4], b[2];
            #pragma unroll
            for (int m = 0; m < 4; ++m) a[m] = *(const f16x8*)&Asr[wr * 64 + m * 16 + cl][sx];
            #pragma unroll
            for (int n = 0; n < 2; ++n) b[n] = *(const f16x8*)&BsM[buf][(wc * 32 + n * 16 + cl) * 64 + sx];
            #pragma unroll
            for (int m = 0; m < 4; ++m)
                #pragma unroll
                for (int n = 0; n < 2; ++n)
                    accR[m][n] = __builtin_amdgcn_mfma_f32_16x16x32_f16(a[m], b[n], accR[m][n], 0, 0, 0);
        }
    };

    A_load(0); B_stageR(0, 0);
    int cur2 = 0;
    #pragma unroll 1
    for (int k = 0; k < 4; ++k) {
        WAITN(2);
        SBAR();
        A_write(); LGKM0();
        if (k < 3) { A_load((k + 1) * 64); B_stageR(cur2 ^ 1, (k + 1) * 64); WAITN(6); }
        else       { WAITN(0); }
        SBAR();
        computeR(cur2);
        cur2 ^= 1;
    }

    const float cda = Cd_p[0] * a_p[0] * sqrtf(2.f * 9.80665f);
    int node[2];
    #pragma unroll
    for (int n = 0; n < 2; ++n) node[n] = n0 + wc * 32 + n * 16 + cl;
    float lsum = 0.f;
    #pragma unroll
    for (int m = 0; m < 4; ++m) {
        #pragma unroll
        for (int reg = 0; reg < 4; ++reg) {
            const int srow = sb + wr * 64 + m * 16 + g * 4 + reg;
            const int idx = leak_id[srow];
            const float nv = net[idx];
            #pragma unroll
            for (int n = 0; n < 2; ++n) {
                const float H = accH[m][n][reg] * T_SCALE;
                const float sq = (H > 0.f) ? sqrtf(H) : 0.f;
                const float dl = cda * (float)MT16[(size_t)idx * N_NODES + node[n]] * sq;
                const float r = accR[m][n][reg] + nv * (float)G2_16[(size_t)idx * N_NODES + node[n]] - dl;
                lsum += r * r;
            }
        }
    }
    #pragma unroll
    for (int off = 32; off > 0; off >>= 1) lsum += __shfl_down(lsum, off, 64);
    __syncthreads();
    float* wred = (float*)&AsM[0][0];
    if (lane == 0) wred[wid] = lsum;
    __syncthreads();
    if (t == 0) {
        float tot = 0.f;
        #pragma unroll
        for (int i = 0; i < 8; ++i) tot += wred[i];
        atomicAdd(out, tot * scale);
    }
}

extern "C" void kernel_launch(void* const* d_in, const int* in_sizes, int n_in,
                              void* d_out, int out_size, void* d_ws, size_t ws_size,
                              hipStream_t stream) {
    const float* D          = (const float*)d_in[0];
    const int*   leak_id    = (const int*)  d_in[1];
    const float* A0         = (const float*)d_in[2];
    const float* inv        = (const float*)d_in[3];
    const float* M          = (const float*)d_in[4];
    const float* supply     = (const float*)d_in[5];
    const float* L          = (const float*)d_in[6];
    const float* dpipe      = (const float*)d_in[7];
    const float* C          = (const float*)d_in[8];
    const float* a_p        = (const float*)d_in[9];
    const float* Cd_p       = (const float*)d_in[10];
    const float* W1         = (const float*)d_in[11];
    const float* b1         = (const float*)d_in[12];
    const float* W2         = (const float*)d_in[13];
    const float* b2         = (const float*)d_in[14];
    const float* W3         = (const float*)d_in[15];
    const float* b3         = (const float*)d_in[16];
    const float* base       = (const float*)d_in[17];
    const int*   demand_idx = (const int*)  d_in[18];

    char* ws = (char*)d_ws;
    size_t off = 0;
    auto carve = [&](size_t bytes) { char* p = ws + off; off += (bytes + 255) & ~(size_t)255; return p; };
    float* net    = (float*)carve(N_PIPES * 4);
    float* lKc    = (float*)carve(N_PIPES * 4);
    f16* inv16  = (f16*)carve((size_t)N_NODES * N_PIPES * 2);
    f16* A016   = (f16*)carve((size_t)N_NODES * N_PIPES * 2);
    f16* MT16   = (f16*)carve((size_t)N_PIPES * N_NODES * 2);
    f16* invT16 = (f16*)carve((size_t)N_PIPES * N_NODES * 2);
    f16* G16    = (f16*)carve((size_t)N_PIPES * N_PIPES * 2);
    f16* G2_16  = (f16*)carve((size_t)N_PIPES * N_NODES * 2);
    f16* Wt     = (f16*)carve((size_t)N_NODES * N_NODES * 2);
    f16* P1p    = (f16*)carve((size_t)N_NODES * N_DEM * 2);
    f16* DI16   = (f16*)carve((size_t)N_DEM * N_PIPES * 2);
    f16* IDXT   = (f16*)carve((size_t)N_PIPES * N_DEM * 2);
    f16* t16    = (f16*)carve((size_t)S_TOTAL * N_PIPES * 2);

    // ---- dispatch 1: all prep (also zeroes d_out) ----
    prep_all<<<1024, 256, 0, stream>>>(
        W1, b1, W2, b2, W3, b3, base, L, dpipe, C,
        M, inv, A0, demand_idx,
        net, lKc, MT16, invT16, inv16, A016, DI16, IDXT,
        (float*)d_out, out_size);

    // ---- dispatch 2: three independent small GEMMs ----
    GemmP pG16 = {MT16, N_NODES, invT16, N_NODES, G16, N_PIPES, N_NODES, nullptr, 16, 8};
    GemmP pWt  = {A016, N_PIPES, inv16, N_PIPES, Wt, N_NODES, N_PIPES, nullptr, 8, 4};
    GemmP pP1  = {A016, N_PIPES, DI16, N_PIPES, P1p, N_DEM, N_PIPES, demand_idx, 4, 4};
    gemm_small3<<<dim3(16, 8, 3), 256, 0, stream>>>(pG16, pWt, pP1);

    // ---- dispatch 3: qt (1024 blocks) + G2 rider (64 blocks) ----
    gemm_qt_mfma<<<dim3(8, 136), 512, 0, stream>>>(
        D, leak_id, IDXT, net, G16, lKc, supply, t16, MT16, Wt, G2_16);

    // ---- dispatch 4: res ----
    const float scale = 1.f / ((float)S_TOTAL * (float)N_NODES);
    gemm_res_mfma<<<dim3(N_NODES / 128, S_TOTAL / 128), 512, 0, stream>>>(
        t16, inv16, D, P1p, MT16, G2_16, leak_id, net, Cd_p, a_p,
        scale, (float*)d_out);
}

// Round 12
// 94.690 us; speedup vs baseline: 1.0412x; 1.0412x over previous
//
#include <hip/hip_runtime.h>
#include <math.h>

typedef _Float16 f16;
typedef _Float16 f16x4 __attribute__((ext_vector_type(4)));
typedef _Float16 f16x8 __attribute__((ext_vector_type(8)));
typedef float f32x4 __attribute__((ext_vector_type(4)));

#define S_TOTAL 16384
#define N_NODES 512
#define N_PIPES 1024
#define N_DEM   256
#define HIDDEN  64
#define T_SCALE 256.0f   // t = (supply - hL)/T_SCALE to fit f16 range; H *= T_SCALE

// direct HBM -> LDS, 16B per lane (wave writes base + lane*16, LINEAR dest)
#define GLOAD16(gsrc, ldst) \
    __builtin_amdgcn_global_load_lds((const __attribute__((address_space(1))) void*)(gsrc), \
                                     (__attribute__((address_space(3))) void*)(ldst), 16, 0, 0)
#define SBAR()  __builtin_amdgcn_s_barrier()
#define FENCE() asm volatile("" ::: "memory")
#define WAITN(n) asm volatile("s_waitcnt vmcnt(" #n ")" ::: "memory")

// ================= fused prep: MLP + transposes + conversions + gathers ========
// blocks [0,256):   MLP (4 waves/block, 1 pipe/wave) + d_out zero (block 0)
// blocks [256,512): transpose M (128) and inv (128) to f16 [C][R]
// blocks [512,1280): grid-stride bulk conversions + gathers
__global__ __launch_bounds__(256) void prep_all(
    const float* __restrict__ W1, const float* __restrict__ b1,
    const float* __restrict__ W2, const float* __restrict__ b2,
    const float* __restrict__ W3, const float* __restrict__ b3,
    const float* __restrict__ base,
    const float* __restrict__ L, const float* __restrict__ dpipe,
    const float* __restrict__ Cw,
    const float* __restrict__ Mf, const float* __restrict__ inv,
    const float* __restrict__ A0, const float* __restrict__ D,
    const int* __restrict__ dmap,
    float* __restrict__ net, float* __restrict__ lKc,
    f16* __restrict__ MT16, f16* __restrict__ invT16,
    f16* __restrict__ inv16, f16* __restrict__ A016, f16* __restrict__ D16,
    f16* __restrict__ DI16, f16* __restrict__ IDXT,
    float* __restrict__ out, int out_size)
{
    __shared__ __align__(16) f16 tile[64][72];
    const int b = blockIdx.x, t = threadIdx.x;
    if (b < 256) {
        if (b == 0) for (int i = t; i < out_size; i += 256) out[i] = 0.f;
        const int wid = t >> 6, k = t & 63;
        const int p = b * 4 + wid;
        const float x = (float)p;
        float h1 = tanhf(x * W1[k] + b1[k]);
        float acc = b2[k];
        #pragma unroll
        for (int j = 0; j < HIDDEN; ++j) {
            float hj = __shfl(h1, j, 64);
            acc = fmaf(hj, W2[j * HIDDEN + k], acc);
        }
        float partial = tanhf(acc) * W3[k];
        #pragma unroll
        for (int off = 32; off > 0; off >>= 1) partial += __shfl_down(partial, off, 64);
        if (k == 0) {
            net[p] = base[p] + partial + b3[0];
            lKc[p] = log2f(10.667f) - 1.852f * log2f(Cw[p]) - 4.871f * log2f(dpipe[p]) + log2f(L[p]);
        }
        return;
    }
    if (b < 512) {
        const int idx = b - 256;
        const float* in = (idx < 128) ? Mf : inv;
        f16* outp = (idx < 128) ? MT16 : invT16;
        const int i2 = idx & 127;
        const int bx = i2 & 15, by = i2 >> 4;   // 16 x 8 tiles of 64x64
        const int r0 = by * 64, c0 = bx * 64;
        const int lr = t / 16, lc4 = (t % 16) * 4;
        #pragma unroll
        for (int i = 0; i < 4; ++i) {
            int r = lr + i * 16;
            float4 v = *(const float4*)(in + (size_t)(r0 + r) * N_PIPES + c0 + lc4);
            tile[lc4 + 0][r] = (f16)v.x; tile[lc4 + 1][r] = (f16)v.y;
            tile[lc4 + 2][r] = (f16)v.z; tile[lc4 + 3][r] = (f16)v.w;
        }
        __syncthreads();
        const int wrow = t / 4, wc16 = (t % 4) * 16;
        *(f16x8*)(outp + (size_t)(c0 + wrow) * N_NODES + r0 + wc16)     = *(f16x8*)&tile[wrow][wc16];
        *(f16x8*)(outp + (size_t)(c0 + wrow) * N_NODES + r0 + wc16 + 8) = *(f16x8*)&tile[wrow][wc16 + 8];
        return;
    }
    const int tid = (b - 512) * 256 + t;
    const int np = 768 * 256;
    for (int i = tid; i < (N_NODES * N_PIPES) / 4; i += np) {
        float4 v = ((const float4*)inv)[i];
        ((f16x4*)inv16)[i] = (f16x4){(f16)v.x, (f16)v.y, (f16)v.z, (f16)v.w};
        float4 w = ((const float4*)A0)[i];
        ((f16x4*)A016)[i] = (f16x4){(f16)w.x, (f16)w.y, (f16)w.z, (f16)w.w};
    }
    for (int i = tid; i < (S_TOTAL * N_DEM) / 4; i += np) {
        float4 v = ((const float4*)D)[i];
        ((f16x4*)D16)[i] = (f16x4){(f16)v.x, (f16)v.y, (f16)v.z, (f16)v.w};
    }
    for (int i = tid; i < N_DEM * (N_PIPES / 4); i += np) {
        int j = i >> 8, p0 = (i & 255) * 4;
        float4 v = *(const float4*)(inv + (size_t)dmap[j] * N_PIPES + p0);
        *(f16x4*)(DI16 + (size_t)j * N_PIPES + p0) = (f16x4){(f16)v.x, (f16)v.y, (f16)v.z, (f16)v.w};
    }
    for (int i = tid; i < N_PIPES * (N_DEM / 4); i += np) {
        int p = i >> 6, j0 = (i & 63) * 4;
        f16x4 o;
        #pragma unroll
        for (int u = 0; u < 4; ++u)
            o[u] = (f16)inv[(size_t)dmap[j0 + u] * N_PIPES + p];
        *(f16x4*)(IDXT + (size_t)p * N_DEM + j0) = o;
    }
}

// ---------------- small MFMA GEMM body (256 thr): C[i][c] = sum_k A[i][k]*B[c][k]
struct GemmP {
    const f16* A; int lda;
    const f16* B; int ldb;
    f16* C; int ldc;
    int K;
    const int* dmap;
    int gx, gy;
};

__device__ __forceinline__ void gemm_body(const GemmP& P, int bx, int by) {
    __shared__ __align__(16) f16 As[128][72], Bs[64][72];
    const int m0 = by * 128, c0 = bx * 64;
    const int t = threadIdx.x, lane = t & 63, wid = t >> 6;
    const int wr = wid >> 1, wc = wid & 1;
    const int cl = lane & 15, g = lane >> 4;
    const int tr = t >> 3, tc = (t & 7) * 8;
    f32x4 acc[4][2] = {};
    for (int k0 = 0; k0 < P.K; k0 += 64) {
        #pragma unroll
        for (int r = 0; r < 4; ++r) {
            int row = r * 32 + tr;
            *(f16x8*)&As[row][tc] = *(const f16x8*)(P.A + (size_t)(m0 + row) * P.lda + k0 + tc);
        }
        #pragma unroll
        for (int r = 0; r < 2; ++r) {
            int row = r * 32 + tr;
            *(f16x8*)&Bs[row][tc] = *(const f16x8*)(P.B + (size_t)(c0 + row) * P.ldb + k0 + tc);
        }
        __syncthreads();
        #pragma unroll
        for (int kk = 0; kk < 2; ++kk) {
            const int kb = kk * 32 + g * 8;
            f16x8 a[4], bfr[2];
            #pragma unroll
            for (int m = 0; m < 4; ++m) a[m] = *(const f16x8*)&As[wr * 64 + m * 16 + cl][kb];
            #pragma unroll
            for (int n = 0; n < 2; ++n) bfr[n] = *(const f16x8*)&Bs[wc * 32 + n * 16 + cl][kb];
            #pragma unroll
            for (int m = 0; m < 4; ++m)
                #pragma unroll
                for (int n = 0; n < 2; ++n)
                    acc[m][n] = __builtin_amdgcn_mfma_f32_16x16x32_f16(a[m], bfr[n], acc[m][n], 0, 0, 0);
        }
        __syncthreads();
    }
    #pragma unroll
    for (int m = 0; m < 4; ++m)
        #pragma unroll
        for (int reg = 0; reg < 4; ++reg) {
            const int row = m0 + wr * 64 + m * 16 + g * 4 + reg;
            #pragma unroll
            for (int n = 0; n < 2; ++n) {
                const int col = c0 + wc * 32 + n * 16 + cl;
                float v = acc[m][n][reg];
                if (P.dmap && P.dmap[col] == row) v -= 1.0f;
                P.C[(size_t)row * P.ldc + col] = (f16)v;
            }
        }
}

__global__ __launch_bounds__(256) void gemm_small3(GemmP p0, GemmP p1, GemmP p2) {
    const GemmP& P = (blockIdx.z == 0) ? p0 : (blockIdx.z == 1) ? p1 : p2;
    if ((int)blockIdx.x >= P.gx || (int)blockIdx.y >= P.gy) return;
    gemm_body(P, blockIdx.x, blockIdx.y);
}

// ======================= gemm_qt + G2 rider (512 thr) ==========================
// y<128: q[s][p] = D16*IDXT^T + nv*G16[idx]; t = (supply - hL)/T_SCALE
//        (round-10 proven path: gload_lds dbuf both operands, vmcnt(4))
// y>=128: G2[i][c] = sum_k MT16[i][k]*Wt[c][k]  (1024x512, K=512)
__global__ __launch_bounds__(512, 4) void gemm_qt_mfma(
    const f16* __restrict__ D16, const int* __restrict__ leak_id,
    const f16* __restrict__ IDXT, const float* __restrict__ net,
    const f16* __restrict__ G16, const float* __restrict__ lKc,
    const float* __restrict__ supply, f16* __restrict__ t16,
    const f16* __restrict__ MT16, const f16* __restrict__ Wt,
    f16* __restrict__ G2out)
{
    __shared__ __align__(16) f16 As[2][128][64];   // 32 KB
    __shared__ __align__(16) f16 Bs[2][128][64];   // 32 KB
    const int t = threadIdx.x, lane = t & 63, wid = t >> 6;

    if (blockIdx.y >= 128) {     // ---------------- G2 rider ----------------
        f16 (*A2)[72] = (f16(*)[72])&Bs[0][0][0];
        f16 (*B2)[72] = (f16(*)[72])&As[0][0][0];
        const int m0 = ((int)blockIdx.y - 128) * 128, c0 = blockIdx.x * 64;
        const int wr = wid >> 2, wc = wid & 3;
        const int cl = lane & 15, g = lane >> 4;
        f32x4 acc[4] = {};
        for (int k0 = 0; k0 < 512; k0 += 64) {
            {
                int r = t >> 2, c16 = (t & 3) * 16;
                *(f16x8*)&A2[r][c16]     = *(const f16x8*)(MT16 + (size_t)(m0 + r) * N_NODES + k0 + c16);
                *(f16x8*)&A2[r][c16 + 8] = *(const f16x8*)(MT16 + (size_t)(m0 + r) * N_NODES + k0 + c16 + 8);
                int r2 = t >> 3, c8 = (t & 7) * 8;
                *(f16x8*)&B2[r2][c8] = *(const f16x8*)(Wt + (size_t)(c0 + r2) * N_NODES + k0 + c8);
            }
            __syncthreads();
            #pragma unroll
            for (int kk = 0; kk < 2; ++kk) {
                const int kb = kk * 32 + g * 8;
                f16x8 b = *(const f16x8*)&B2[wc * 16 + cl][kb];
                #pragma unroll
                for (int m = 0; m < 4; ++m) {
                    f16x8 a = *(const f16x8*)&A2[wr * 64 + m * 16 + cl][kb];
                    acc[m] = __builtin_amdgcn_mfma_f32_16x16x32_f16(a, b, acc[m], 0, 0, 0);
                }
            }
            __syncthreads();
        }
        #pragma unroll
        for (int m = 0; m < 4; ++m)
            #pragma unroll
            for (int reg = 0; reg < 4; ++reg)
                G2out[(size_t)(m0 + wr * 64 + m * 16 + g * 4 + reg) * N_NODES + c0 + wc * 16 + cl] = (f16)acc[m][reg];
        return;
    }
    // ---------------- qt tiles (round-10 schedule) ----------------
    const int bid = blockIdx.y * 8 + blockIdx.x;           // 1024 blocks
    const int w = (bid & 7) * 128 + (bid >> 3);            // XCD-contiguous
    const int bx = w & 7, by = w >> 3;
    const int p0 = bx * 128, sb = by * 128;
    const int wr = wid >> 2, wc = wid & 3;                 // 2 x 4 waves
    const int cl = lane & 15, g = lane >> 4;
    const int swrow = lane >> 3;
    const int swcol = ((lane & 7) ^ swrow) * 8;
    const int sx0 = (g ^ (cl & 7)) * 8, sx1 = ((4 + g) ^ (cl & 7)) * 8;

    const f16* Abase = D16 + (size_t)(sb + swrow) * N_DEM + swcol;
    const f16* Bbase = IDXT + (size_t)(p0 + swrow) * N_DEM + swcol;

    f32x4 acc[4][2] = {};
    auto stage = [&](int buf, int k0) {
        #pragma unroll
        for (int c = 0; c < 2; ++c) {
            int r0 = c * 64 + wid * 8;
            GLOAD16(Abase + (size_t)r0 * N_DEM + k0, &As[buf][r0][0]);
        }
        #pragma unroll
        for (int c = 0; c < 2; ++c) {
            int r0 = c * 64 + wid * 8;
            GLOAD16(Bbase + (size_t)r0 * N_DEM + k0, &Bs[buf][r0][0]);
        }
    };
    auto compute = [&](int buf) {
        #pragma unroll
        for (int kk = 0; kk < 2; ++kk) {
            const int sx = kk ? sx1 : sx0;
            f16x8 a[4], b[2];
            #pragma unroll
            for (int m = 0; m < 4; ++m) a[m] = *(const f16x8*)&As[buf][wr * 64 + m * 16 + cl][sx];
            #pragma unroll
            for (int n = 0; n < 2; ++n) b[n] = *(const f16x8*)&Bs[buf][wc * 32 + n * 16 + cl][sx];
            #pragma unroll
            for (int m = 0; m < 4; ++m)
                #pragma unroll
                for (int n = 0; n < 2; ++n)
                    acc[m][n] = __builtin_amdgcn_mfma_f32_16x16x32_f16(a[m], b[n], acc[m][n], 0, 0, 0);
        }
    };

    int cur = 0;
    stage(0, 0);
    #pragma unroll 1
    for (int k = 0; k < 3; ++k) {
        stage(cur ^ 1, (k + 1) * 64);
        WAITN(4); SBAR();
        compute(cur);
        FENCE(); SBAR();
        cur ^= 1;
    }
    WAITN(0); SBAR();
    compute(cur);

    float lKc2[2], sup2[2]; int pcol[2];
    #pragma unroll
    for (int n = 0; n < 2; ++n) {
        pcol[n] = p0 + wc * 32 + n * 16 + cl;
        lKc2[n] = lKc[pcol[n]]; sup2[n] = supply[pcol[n]];
    }
    #pragma unroll
    for (int m = 0; m < 4; ++m) {
        #pragma unroll
        for (int reg = 0; reg < 4; ++reg) {
            const int srow = sb + wr * 64 + m * 16 + g * 4 + reg;
            const int idx = leak_id[srow];
            const float nv = net[idx];
            #pragma unroll
            for (int n = 0; n < 2; ++n) {
                float qv = acc[m][n][reg] + nv * (float)G16[(size_t)idx * N_PIPES + pcol[n]];
                float l = __builtin_amdgcn_logf(fabsf(qv));
                float hL = copysignf(__builtin_amdgcn_exp2f(fmaf(1.852f, l, lKc2[n])), qv);
                t16[(size_t)srow * N_PIPES + pcol[n]] = (f16)((sup2[n] - hL) * (1.0f / T_SCALE));
            }
        }
    }
}

// ======================= gemm_res (128x128, 8 waves, dbuf, swizzle) ============
// accH = t*inv^T (K=1024); accR = D16*P1'^T (K=256); r = accR + nv*G2[idx] - dleak
__global__ __launch_bounds__(512, 4) void gemm_res_mfma(
    const f16* __restrict__ t16, const f16* __restrict__ inv16,
    const f16* __restrict__ D16, const f16* __restrict__ P1p,
    const f16* __restrict__ MT16, const f16* __restrict__ G2_16,
    const int* __restrict__ leak_id, const float* __restrict__ net,
    const float* __restrict__ Cd_p, const float* __restrict__ a_p,
    float scale, float* __restrict__ out)
{
    __shared__ __align__(16) f16 As[2][128][64];
    __shared__ __align__(16) f16 Bs[2][128][64];
    const int nwg = gridDim.x * gridDim.y;
    const int bid = blockIdx.y * gridDim.x + blockIdx.x;
    const int w = (bid & 7) * (nwg >> 3) + (bid >> 3);
    const int bx = w % gridDim.x, by = w / gridDim.x;
    const int n0 = bx * 128, sb = by * 128;
    const int t = threadIdx.x, lane = t & 63, wid = t >> 6;
    const int wr = wid >> 2, wc = wid & 3;
    const int cl = lane & 15, g = lane >> 4;
    const int swrow = lane >> 3;
    const int swcol = ((lane & 7) ^ swrow) * 8;
    const int sx0 = (g ^ (cl & 7)) * 8, sx1 = ((4 + g) ^ (cl & 7)) * 8;

    const f16* HAb = t16   + (size_t)(sb + swrow) * N_PIPES + swcol;
    const f16* HBb = inv16 + (size_t)(n0 + swrow) * N_PIPES + swcol;
    const f16* RAb = D16   + (size_t)(sb + swrow) * N_DEM + swcol;
    const f16* RBb = P1p   + (size_t)(n0 + swrow) * N_DEM + swcol;

    f32x4 accH[4][2] = {}, accR[4][2] = {};

    auto stageH = [&](int buf, int k0) {
        #pragma unroll
        for (int c = 0; c < 2; ++c) {
            int r0 = c * 64 + wid * 8;
            GLOAD16(HAb + (size_t)r0 * N_PIPES + k0, &As[buf][r0][0]);
        }
        #pragma unroll
        for (int c = 0; c < 2; ++c) {
            int r0 = c * 64 + wid * 8;
            GLOAD16(HBb + (size_t)r0 * N_PIPES + k0, &Bs[buf][r0][0]);
        }
    };
    auto stageR = [&](int buf, int k0) {
        #pragma unroll
        for (int c = 0; c < 2; ++c) {
            int r0 = c * 64 + wid * 8;
            GLOAD16(RAb + (size_t)r0 * N_DEM + k0, &As[buf][r0][0]);
        }
        #pragma unroll
        for (int c = 0; c < 2; ++c) {
            int r0 = c * 64 + wid * 8;
            GLOAD16(RBb + (size_t)r0 * N_DEM + k0, &Bs[buf][r0][0]);
        }
    };
    auto computeT = [&](int buf, f32x4 (&accA)[4][2]) {
        #pragma unroll
        for (int kk = 0; kk < 2; ++kk) {
            const int sx = kk ? sx1 : sx0;
            f16x8 a[4], b[2];
            #pragma unroll
            for (int m = 0; m < 4; ++m) a[m] = *(const f16x8*)&As[buf][wr * 64 + m * 16 + cl][sx];
            #pragma unroll
            for (int n = 0; n < 2; ++n) b[n] = *(const f16x8*)&Bs[buf][wc * 32 + n * 16 + cl][sx];
            #pragma unroll
            for (int m = 0; m < 4; ++m)
                #pragma unroll
                for (int n = 0; n < 2; ++n)
                    accA[m][n] = __builtin_amdgcn_mfma_f32_16x16x32_f16(a[m], b[n], accA[m][n], 0, 0, 0);
        }
    };

    int cur = 0;
    stageH(0, 0);
    #pragma unroll 1
    for (int k = 0; k < 15; ++k) {
        stageH(cur ^ 1, (k + 1) * 64);
        WAITN(4); SBAR();
        computeT(cur, accH);
        FENCE(); SBAR();
        cur ^= 1;
    }
    // last H iter: prefetch first R tile into the other buffer
    stageR(cur ^ 1, 0);
    WAITN(4); SBAR();
    computeT(cur, accH);
    FENCE(); SBAR();
    cur ^= 1;
    #pragma unroll 1
    for (int k = 0; k < 3; ++k) {
        stageR(cur ^ 1, (k + 1) * 64);
        WAITN(4); SBAR();
        computeT(cur, accR);
        FENCE(); SBAR();
        cur ^= 1;
    }
    WAITN(0); SBAR();
    computeT(cur, accR);

    const float cda = Cd_p[0] * a_p[0] * sqrtf(2.f * 9.80665f);
    int node[2];
    #pragma unroll
    for (int n = 0; n < 2; ++n) node[n] = n0 + wc * 32 + n * 16 + cl;
    float lsum = 0.f;
    #pragma unroll
    for (int m = 0; m < 4; ++m) {
        #pragma unroll
        for (int reg = 0; reg < 4; ++reg) {
            const int srow = sb + wr * 64 + m * 16 + g * 4 + reg;
            const int idx = leak_id[srow];
            const float nv = net[idx];
            #pragma unroll
            for (int n = 0; n < 2; ++n) {
                const float H = accH[m][n][reg] * T_SCALE;
                const float sq = (H > 0.f) ? sqrtf(H) : 0.f;
                const float dl = cda * (float)MT16[(size_t)idx * N_NODES + node[n]] * sq;
                const float r = accR[m][n][reg] + nv * (float)G2_16[(size_t)idx * N_NODES + node[n]] - dl;
                lsum += r * r;
            }
        }
    }
    #pragma unroll
    for (int off = 32; off > 0; off >>= 1) lsum += __shfl_down(lsum, off, 64);
    __syncthreads();
    float* wred = (float*)&As[0][0][0];
    if (lane == 0) wred[wid] = lsum;
    __syncthreads();
    if (t == 0) {
        float tot = 0.f;
        #pragma unroll
        for (int i = 0; i < 8; ++i) tot += wred[i];
        atomicAdd(out, tot * scale);
    }
}

extern "C" void kernel_launch(void* const* d_in, const int* in_sizes, int n_in,
                              void* d_out, int out_size, void* d_ws, size_t ws_size,
                              hipStream_t stream) {
    const float* D          = (const float*)d_in[0];
    const int*   leak_id    = (const int*)  d_in[1];
    const float* A0         = (const float*)d_in[2];
    const float* inv        = (const float*)d_in[3];
    const float* M          = (const float*)d_in[4];
    const float* supply     = (const float*)d_in[5];
    const float* L          = (const float*)d_in[6];
    const float* dpipe      = (const float*)d_in[7];
    const float* C          = (const float*)d_in[8];
    const float* a_p        = (const float*)d_in[9];
    const float* Cd_p       = (const float*)d_in[10];
    const float* W1         = (const float*)d_in[11];
    const float* b1         = (const float*)d_in[12];
    const float* W2         = (const float*)d_in[13];
    const float* b2         = (const float*)d_in[14];
    const float* W3         = (const float*)d_in[15];
    const float* b3         = (const float*)d_in[16];
    const float* base       = (const float*)d_in[17];
    const int*   demand_idx = (const int*)  d_in[18];

    char* ws = (char*)d_ws;
    size_t off = 0;
    auto carve = [&](size_t bytes) { char* p = ws + off; off += (bytes + 255) & ~(size_t)255; return p; };
    float* net    = (float*)carve(N_PIPES * 4);
    float* lKc    = (float*)carve(N_PIPES * 4);
    f16* inv16  = (f16*)carve((size_t)N_NODES * N_PIPES * 2);
    f16* A016   = (f16*)carve((size_t)N_NODES * N_PIPES * 2);
    f16* MT16   = (f16*)carve((size_t)N_PIPES * N_NODES * 2);
    f16* invT16 = (f16*)carve((size_t)N_PIPES * N_NODES * 2);
    f16* G16    = (f16*)carve((size_t)N_PIPES * N_PIPES * 2);
    f16* G2_16  = (f16*)carve((size_t)N_PIPES * N_NODES * 2);
    f16* Wt     = (f16*)carve((size_t)N_NODES * N_NODES * 2);
    f16* P1p    = (f16*)carve((size_t)N_NODES * N_DEM * 2);
    f16* DI16   = (f16*)carve((size_t)N_DEM * N_PIPES * 2);
    f16* IDXT   = (f16*)carve((size_t)N_PIPES * N_DEM * 2);
    f16* D16    = (f16*)carve((size_t)S_TOTAL * N_DEM * 2);
    f16* t16    = (f16*)carve((size_t)S_TOTAL * N_PIPES * 2);

    // ---- dispatch 1: all prep (also zeroes d_out) ----
    prep_all<<<1280, 256, 0, stream>>>(
        W1, b1, W2, b2, W3, b3, base, L, dpipe, C,
        M, inv, A0, D, demand_idx,
        net, lKc, MT16, invT16, inv16, A016, D16, DI16, IDXT,
        (float*)d_out, out_size);

    // ---- dispatch 2: three independent small GEMMs ----
    GemmP pG16 = {MT16, N_NODES, invT16, N_NODES, G16, N_PIPES, N_NODES, nullptr, 16, 8};
    GemmP pWt  = {A016, N_PIPES, inv16, N_PIPES, Wt, N_NODES, N_PIPES, nullptr, 8, 4};
    GemmP pP1  = {A016, N_PIPES, DI16, N_PIPES, P1p, N_DEM, N_PIPES, demand_idx, 4, 4};
    gemm_small3<<<dim3(16, 8, 3), 256, 0, stream>>>(pG16, pWt, pP1);

    // ---- dispatch 3: qt (1024 blocks) + G2 rider (64 blocks) ----
    gemm_qt_mfma<<<dim3(8, 136), 512, 0, stream>>>(
        D16, leak_id, IDXT, net, G16, lKc, supply, t16, MT16, Wt, G2_16);

    // ---- dispatch 4: res ----
    const float scale = 1.f / ((float)S_TOTAL * (float)N_NODES);
    gemm_res_mfma<<<dim3(N_NODES / 128, S_TOTAL / 128), 512, 0, stream>>>(
        t16, inv16, D16, P1p, MT16, G2_16, leak_id, net, Cd_p, a_p,
        scale, (float*)d_out);
}